// Round 9
// baseline (1182.101 us; speedup 1.0000x reference)
//
#include <hip/hip_runtime.h>

// ============================================================================
// RetinaNetHead (S2ANet-style rotated head), MI355X gfx950.
// R9: T4 counted-wait depth-2 pipeline in the conv kernels. R8's __syncthreads
//     (auto vmcnt(0)) waited on the stage issued ~300cyc earlier IN the same
//     phase -> exposed HBM latency every phase (MfmaUtil stuck at 41%).
//     Now: {s_waitcnt vmcnt(0) for stage(ph) issued ONE FULL PHASE ago;
//     s_barrier; sched_barrier(0); stage(ph+1); compute(ph)} -- one barrier
//     per phase, wait covers a whole phase of flight time.
// Everything else identical to R8 (BK=32 dbuf, XOR swizzle rule#21, vectorized
// LDS epilogue, merged dispatches). fp32 accum; logits/decode fp32.
//
// Level geometry: rows gm 0..174591; cum={0,131072,163840,172032,174080,174592}
// Workspace (ushort units), same footprint (~245.1MB):
//   [0) feats NHWC fp16 (reused as t2) | [44,695,552) t1r | [78,249,984) t1c
//   [111,804,416) conv w 4x[9][256][256] | [114,163,712) wh | [114,171,904) wc
//   [114,188,288) zp | byte 228,376,704: hbuf fp32 [174592][24]
// ============================================================================

typedef __attribute__((ext_vector_type(8))) _Float16 f16x8;
typedef __attribute__((ext_vector_type(4))) float f32x4;

#define SCORES_TOTAL 10475520ull  // 8*87296*15

__device__ __forceinline__ unsigned short f2h(float f) {
  union { _Float16 h; unsigned short u; } x;
  x.h = (_Float16)f;
  return x.u;
}

__device__ __forceinline__ float sigmf(float x) {
  return 1.0f / (1.0f + expf(-x));
}

__device__ __forceinline__ void gload_lds16(const unsigned short* g,
                                            unsigned short* l) {
  __builtin_amdgcn_global_load_lds(
      (const __attribute__((address_space(1))) unsigned int*)g,
      (__attribute__((address_space(3))) unsigned int*)l, 16, 0, 0);
}

__device__ __forceinline__ void lvl_lookup(int gm, int& logW, int& mbase) {
  if (gm < 131072) { logW = 7; mbase = 0; }
  else if (gm < 163840) { logW = 6; mbase = 131072; }
  else if (gm < 172032) { logW = 5; mbase = 163840; }
  else if (gm < 174080) { logW = 4; mbase = 172032; }
  else { logW = 3; mbase = 174080; }
}

// ---------------------------------------------------------------- weight prep
__global__ __launch_bounds__(256) void prep_convw(
    const float* __restrict__ w0, const float* __restrict__ w1,
    const float* __restrict__ w2, const float* __restrict__ w3,
    unsigned short* __restrict__ wtout) {
  int g = blockIdx.x * 256 + threadIdx.x;  // < 4*589824
  int q = g >> 16;
  int wsel = q / 9;
  int kk = q - wsel * 9;
  int r = g & 65535;
  int oc = r >> 8, ic = r & 255;
  const float* src = (wsel == 0) ? w0 : (wsel == 1) ? w1 : (wsel == 2) ? w2 : w3;
  float v = src[(size_t)(oc * 256 + ic) * 9 + kk];
  wtout[(size_t)wsel * 589824 + (size_t)((kk << 8) + oc) * 256 + ic] = f2h(v);
}

__global__ __launch_bounds__(256) void prep_small(
    const float* __restrict__ clsh, const float* __restrict__ regh,
    const float* __restrict__ confw,
    unsigned short* __restrict__ wc, unsigned short* __restrict__ wh,
    unsigned short* __restrict__ zp) {
  int g = blockIdx.x * 256 + threadIdx.x;
  if (g < 16384) {
    int row = g >> 8, ic = g & 255;
    float v = (row < 60) ? clsh[row * 256 + ic] : 0.0f;
    wc[g] = f2h(v);
  } else if (g < 24576) {
    int gg = g - 16384;
    int row = gg >> 8, ic = gg & 255;
    float v = 0.0f;
    if (row < 20) v = regh[row * 256 + ic];
    else if (row < 24) v = confw[(row - 20) * 256 + ic];
    wh[gg] = f2h(v);
  } else if (g < 24640) {
    zp[g - 24576] = 0;
  }
}

// ------------------------------- NCHW fp32 -> NHWC fp16, all levels merged
__global__ __launch_bounds__(256) void to_nhwc_all(
    const float* __restrict__ f0, const float* __restrict__ f1,
    const float* __restrict__ f2, const float* __restrict__ f3,
    const float* __restrict__ f4, unsigned short* __restrict__ out) {
  __shared__ unsigned short L[64][258];
  const int t = threadIdx.x;
  const int gm0 = blockIdx.x * 64;
  int logW, mbase;
  const float* in;
  if (gm0 < 131072) { logW = 7; mbase = 0; in = f0; }
  else if (gm0 < 163840) { logW = 6; mbase = 131072; in = f1; }
  else if (gm0 < 172032) { logW = 5; mbase = 163840; in = f2; }
  else if (gm0 < 174080) { logW = 4; mbase = 172032; in = f3; }
  else { logW = 3; mbase = 174080; in = f4; }
  const int logHW = 2 * logW;
  const int HW = 1 << logHW;
  const int lm0 = gm0 - mbase;
  const int b = lm0 >> logHW;
  const int hw0 = lm0 & (HW - 1);
#pragma unroll
  for (int it = 0; it < 16; ++it) {
    int c = it * 16 + (t >> 4);
    int j4 = (t & 15) * 4;
    float4 v = *reinterpret_cast<const float4*>(
        in + (size_t)(b * 256 + c) * HW + hw0 + j4);
    L[j4 + 0][c] = f2h(v.x);
    L[j4 + 1][c] = f2h(v.y);
    L[j4 + 2][c] = f2h(v.z);
    L[j4 + 3][c] = f2h(v.w);
  }
  __syncthreads();
#pragma unroll
  for (int it = 0; it < 16; ++it) {
    int j = it * 4 + (t >> 6);
    int c4 = (t & 63) * 4;
    unsigned v0 = (unsigned)L[j][c4 + 0] | ((unsigned)L[j][c4 + 1] << 16);
    unsigned v1 = (unsigned)L[j][c4 + 2] | ((unsigned)L[j][c4 + 3] << 16);
    uint2 v = make_uint2(v0, v1);
    *reinterpret_cast<uint2*>(out + ((size_t)(gm0 + j) << 8) + c4) = v;
  }
}

// --------------------------- conv1 both towers fused: 128Mx128N, BK32 dbuf
__global__ __launch_bounds__(256, 2) void conv1f(
    const unsigned short* __restrict__ xin,   // absolute rows [gm][256]
    const unsigned short* __restrict__ wtR,
    const unsigned short* __restrict__ wtC,
    const float* __restrict__ biasR, const float* __restrict__ biasC,
    const unsigned short* __restrict__ zp,
    unsigned short* __restrict__ outR,        // group-local rows
    unsigned short* __restrict__ outC, int gm_base) {
  __shared__ unsigned short pool[24576];      // A 2x4096 | BR 2x4096 | BC 2x4096
  const int t = threadIdx.x;
  const int lane = t & 63;
  const int wv = t >> 6;
  const int wm = wv >> 1, wn = wv & 1;
  const int gm0 = gm_base + blockIdx.x * 128;
  const int n0 = blockIdx.y << 7;
  int logW, mbase;
  lvl_lookup(gm0, logW, mbase);
  const int logHW = 2 * logW;
  const int H = 1 << logW, W = H;
  const int HWm1 = (1 << logHW) - 1, Wm1 = W - 1;

  const int srow = lane >> 2;                               // 0..15
  const int schk = (((lane & 3) ^ ((lane >> 3) & 3)) << 3); // swizzled src chunk
  int hjj[2], wjj[2];
  const unsigned short* aptrj[2];
  const unsigned short* bRj[2];
  const unsigned short* bCj[2];
  const int sldrow = (wv << 5);
#pragma unroll
  for (int j = 0; j < 2; ++j) {
    int gm = gm0 + sldrow + (j << 4) + srow;
    int lm = gm - mbase;
    int hw = lm & HWm1;
    hjj[j] = hw >> logW;
    wjj[j] = hw & Wm1;
    aptrj[j] = xin + ((size_t)gm << 8) + schk;
    int br = n0 + sldrow + (j << 4) + srow;
    bRj[j] = wtR + ((size_t)br << 8) + schk;
    bCj[j] = wtC + ((size_t)br << 8) + schk;
  }

  f32x4 accR[4][4], accC[4][4];
#pragma unroll
  for (int i = 0; i < 4; ++i)
#pragma unroll
    for (int j = 0; j < 4; ++j) {
      accR[i][j] = (f32x4){0.f, 0.f, 0.f, 0.f};
      accC[i][j] = (f32x4){0.f, 0.f, 0.f, 0.f};
    }

  const int arow = (wm << 6) + (lane & 15);
  const int brow = (wn << 6) + (lane & 15);
  const int sxor = ((lane & 15) >> 1) & 3;
  const int achk = (((lane >> 4) ^ sxor) << 3);

  // ---- prologue: stage phase 0 into buf 0
  {
    const int moff = (-W - 1) << 8;  // kk=0: dy=-1,dx=-1
#pragma unroll
    for (int j = 0; j < 2; ++j) {
      bool valid = (hjj[j] > 0) & (wjj[j] > 0);
      const unsigned short* g = valid ? (aptrj[j] + moff) : zp;
      gload_lds16(g, pool + ((sldrow + (j << 4)) << 5));
    }
#pragma unroll
    for (int j = 0; j < 2; ++j) {
      gload_lds16(bRj[j], pool + 8192 + ((sldrow + (j << 4)) << 5));
      gload_lds16(bCj[j], pool + 16384 + ((sldrow + (j << 4)) << 5));
    }
  }

  int cur = 0;
#pragma unroll 1
  for (int ph = 0; ph < 72; ++ph) {
    // wait for stage(ph) -- issued one full phase ago -- then cross-wave sync
    asm volatile("s_waitcnt vmcnt(0)" ::: "memory");
    __builtin_amdgcn_s_barrier();
    __builtin_amdgcn_sched_barrier(0);
    if (ph < 71) {  // stage phase ph+1 into buf cur^1
      const int p = ph + 1;
      const int kk = p >> 3;
      const int k3 = kk / 3;
      const int dy = k3 - 1, dxv = kk - k3 * 3 - 1;
      const int moff = ((dy << logW) + dxv) << 8;
      const int ic0 = (p & 7) << 5;
      const int nb = (cur ^ 1) << 12;
      const int bko = (kk << 16) + ic0;
#pragma unroll
      for (int j = 0; j < 2; ++j) {
        bool valid = ((unsigned)(hjj[j] + dy) < (unsigned)H) &
                     ((unsigned)(wjj[j] + dxv) < (unsigned)W);
        const unsigned short* g = valid ? (aptrj[j] + moff + ic0) : zp;
        gload_lds16(g, pool + nb + ((sldrow + (j << 4)) << 5));
      }
#pragma unroll
      for (int j = 0; j < 2; ++j) {
        gload_lds16(bRj[j] + bko, pool + 8192 + nb + ((sldrow + (j << 4)) << 5));
        gload_lds16(bCj[j] + bko, pool + 16384 + nb + ((sldrow + (j << 4)) << 5));
      }
    }
    // compute from buf cur
    const int cb = cur << 12;
    f16x8 a[4], bR[4], bC[4];
#pragma unroll
    for (int mf = 0; mf < 4; ++mf)
      a[mf] = *reinterpret_cast<const f16x8*>(
          pool + cb + ((arow + (mf << 4)) << 5) + achk);
#pragma unroll
    for (int nf = 0; nf < 4; ++nf) {
      bR[nf] = *reinterpret_cast<const f16x8*>(
          pool + 8192 + cb + ((brow + (nf << 4)) << 5) + achk);
      bC[nf] = *reinterpret_cast<const f16x8*>(
          pool + 16384 + cb + ((brow + (nf << 4)) << 5) + achk);
    }
#pragma unroll
    for (int mf = 0; mf < 4; ++mf)
#pragma unroll
      for (int nf = 0; nf < 4; ++nf) {
        accR[mf][nf] = __builtin_amdgcn_mfma_f32_16x16x32_f16(
            a[mf], bR[nf], accR[mf][nf], 0, 0, 0);
        accC[mf][nf] = __builtin_amdgcn_mfma_f32_16x16x32_f16(
            a[mf], bC[nf], accC[mf][nf], 0, 0, 0);
      }
    cur ^= 1;
  }
  __syncthreads();  // all reads retired before epilogue overwrites pool

  // ---- vectorized epilogue: acc -> LDS f16 -> 16B stores
  const int erow = t >> 1;
  const int ech = t & 1;
  const unsigned short* esrc =
      pool + ((((erow >> 6) << 1) + ech) << 12) + ((erow & 63) << 6);
  unsigned short* ep = pool + (wv << 12);
  const int eg = (lane >> 4) << 2;
  const int el = lane & 15;
  const int lrow0 = gm0 - gm_base;

#pragma unroll
  for (int nf = 0; nf < 4; ++nf) {
    float bi = biasR[n0 + (wn << 6) + (nf << 4) + el];
#pragma unroll
    for (int mf = 0; mf < 4; ++mf)
#pragma unroll
      for (int r = 0; r < 4; ++r)
        ep[((mf << 4) + eg + r) * 64 + (nf << 4) + el] =
            f2h(fmaxf(accR[mf][nf][r] + bi, 0.0f));
  }
  __syncthreads();
  {
    unsigned short* edst =
        outR + ((size_t)(lrow0 + erow) << 8) + n0 + (ech << 6);
#pragma unroll
    for (int q = 0; q < 8; ++q)
      reinterpret_cast<uint4*>(edst)[q] =
          reinterpret_cast<const uint4*>(esrc)[q];
  }
  __syncthreads();
#pragma unroll
  for (int nf = 0; nf < 4; ++nf) {
    float bi = biasC[n0 + (wn << 6) + (nf << 4) + el];
#pragma unroll
    for (int mf = 0; mf < 4; ++mf)
#pragma unroll
      for (int r = 0; r < 4; ++r)
        ep[((mf << 4) + eg + r) * 64 + (nf << 4) + el] =
            f2h(fmaxf(accC[mf][nf][r] + bi, 0.0f));
  }
  __syncthreads();
  {
    unsigned short* edst =
        outC + ((size_t)(lrow0 + erow) << 8) + n0 + (ech << 6);
#pragma unroll
    for (int q = 0; q < 8; ++q)
      reinterpret_cast<uint4*>(edst)[q] =
          reinterpret_cast<const uint4*>(esrc)[q];
  }
}

// ----------------------------- conv2: 128Mx256N block, BK32 dbuf
__global__ __launch_bounds__(256, 2) void conv2w(
    const unsigned short* __restrict__ xin,  // group-local rows
    const unsigned short* __restrict__ wt,
    const float* __restrict__ bias,
    const unsigned short* __restrict__ zp,
    unsigned short* __restrict__ yout,       // absolute rows
    int gm_base) {
  __shared__ unsigned short pool[24576];     // A 2x4096 | B 2x8192
  const int t = threadIdx.x;
  const int lane = t & 63;
  const int wv = t >> 6;
  const int wm = wv >> 1, wn = wv & 1;       // wave tile 64M x 128N
  const int gm0 = gm_base + blockIdx.x * 128;
  int logW, mbase;
  lvl_lookup(gm0, logW, mbase);
  const int logHW = 2 * logW;
  const int H = 1 << logW, W = H;
  const int HWm1 = (1 << logHW) - 1, Wm1 = W - 1;

  const int srow = lane >> 2;
  const int schk = (((lane & 3) ^ ((lane >> 3) & 3)) << 3);
  int hjj[2], wjj[2];
  const unsigned short* aptrj[2];
  const int sldrow = (wv << 5);
#pragma unroll
  for (int j = 0; j < 2; ++j) {
    int gm = gm0 + sldrow + (j << 4) + srow;
    int lm = gm - mbase;
    int hw = lm & HWm1;
    hjj[j] = hw >> logW;
    wjj[j] = hw & Wm1;
    aptrj[j] = xin + ((size_t)(gm - gm_base) << 8) + schk;
  }
  const unsigned short* bpj[4];
#pragma unroll
  for (int j = 0; j < 4; ++j) {
    int row = (wv << 6) + (j << 4) + srow;   // 0..255
    bpj[j] = wt + ((size_t)row << 8) + schk;
  }

  f32x4 acc[4][8];
#pragma unroll
  for (int i = 0; i < 4; ++i)
#pragma unroll
    for (int j = 0; j < 8; ++j) acc[i][j] = (f32x4){0.f, 0.f, 0.f, 0.f};

  const int arow = (wm << 6) + (lane & 15);
  const int brow = (wn << 7) + (lane & 15);
  const int sxor = ((lane & 15) >> 1) & 3;
  const int achk = (((lane >> 4) ^ sxor) << 3);

  // prologue: stage phase 0 (kk=0: dy=-1,dx=-1) into buf 0
  {
    const int moff = (-W - 1) << 8;
#pragma unroll
    for (int j = 0; j < 2; ++j) {
      bool valid = (hjj[j] > 0) & (wjj[j] > 0);
      const unsigned short* g = valid ? (aptrj[j] + moff) : zp;
      gload_lds16(g, pool + ((sldrow + (j << 4)) << 5));
    }
#pragma unroll
    for (int j = 0; j < 4; ++j)
      gload_lds16(bpj[j], pool + 8192 + (((wv << 6) + (j << 4)) << 5));
  }

  int cur = 0;
#pragma unroll 1
  for (int ph = 0; ph < 72; ++ph) {
    asm volatile("s_waitcnt vmcnt(0)" ::: "memory");
    __builtin_amdgcn_s_barrier();
    __builtin_amdgcn_sched_barrier(0);
    if (ph < 71) {
      const int p = ph + 1;
      const int kk = p >> 3;
      const int k3 = kk / 3;
      const int dy = k3 - 1, dxv = kk - k3 * 3 - 1;
      const int moff = ((dy << logW) + dxv) << 8;
      const int ic0 = (p & 7) << 5;
      const int bko = (kk << 16) + ic0;
#pragma unroll
      for (int j = 0; j < 2; ++j) {
        bool valid = ((unsigned)(hjj[j] + dy) < (unsigned)H) &
                     ((unsigned)(wjj[j] + dxv) < (unsigned)W);
        const unsigned short* g = valid ? (aptrj[j] + moff + ic0) : zp;
        gload_lds16(g, pool + ((cur ^ 1) << 12) + ((sldrow + (j << 4)) << 5));
      }
#pragma unroll
      for (int j = 0; j < 4; ++j)
        gload_lds16(bpj[j] + bko, pool + 8192 + ((cur ^ 1) << 13) +
                                      (((wv << 6) + (j << 4)) << 5));
    }
    const int cbA = cur << 12;
    const int cbB = cur << 13;
    f16x8 a[4], b[8];
#pragma unroll
    for (int mf = 0; mf < 4; ++mf)
      a[mf] = *reinterpret_cast<const f16x8*>(
          pool + cbA + ((arow + (mf << 4)) << 5) + achk);
#pragma unroll
    for (int nf = 0; nf < 8; ++nf)
      b[nf] = *reinterpret_cast<const f16x8*>(
          pool + 8192 + cbB + ((brow + (nf << 4)) << 5) + achk);
#pragma unroll
    for (int mf = 0; mf < 4; ++mf)
#pragma unroll
      for (int nf = 0; nf < 8; ++nf)
        acc[mf][nf] = __builtin_amdgcn_mfma_f32_16x16x32_f16(
            a[mf], b[nf], acc[mf][nf], 0, 0, 0);
    cur ^= 1;
  }
  __syncthreads();  // all reads retired before epilogue overwrites pool

  // ---- vectorized epilogue, two 64-col halves
  const int erow = t >> 1;
  const int ech = t & 1;
  const unsigned short* esrc =
      pool + ((((erow >> 6) << 1) + ech) << 12) + ((erow & 63) << 6);
  unsigned short* ep = pool + (wv << 12);
  const int eg = (lane >> 4) << 2;
  const int el = lane & 15;

#pragma unroll
  for (int h = 0; h < 2; ++h) {
    if (h) __syncthreads();
#pragma unroll
    for (int q4 = 0; q4 < 4; ++q4) {
      int nf = (h << 2) + q4;
      float bi = bias[(wn << 7) + (nf << 4) + el];
#pragma unroll
      for (int mf = 0; mf < 4; ++mf)
#pragma unroll
        for (int r = 0; r < 4; ++r)
          ep[((mf << 4) + eg + r) * 64 + (q4 << 4) + el] =
              f2h(fmaxf(acc[mf][nf][r] + bi, 0.0f));
    }
    __syncthreads();
    unsigned short* edst =
        yout + ((size_t)(gm0 + erow) << 8) + (ech << 7) + (h << 6);
#pragma unroll
    for (int q = 0; q < 8; ++q)
      reinterpret_cast<uint4*>(edst)[q] =
          reinterpret_cast<const uint4*>(esrc)[q];
  }
}

// -------------------------------------------- bbox(20)+conf(4) head -> hbuf
__global__ __launch_bounds__(256) void head24_mfma(
    const unsigned short* __restrict__ t2,  // group-local rows
    const unsigned short* __restrict__ wh,
    const float* __restrict__ regb, const float* __restrict__ confb,
    float* __restrict__ hbuf) {             // group-local rows
  const int t = threadIdx.x, lane = t & 63, wv = t >> 6;
  const int rowb = blockIdx.x * 256 + wv * 64;
  const int kgrp = (lane >> 4) << 3;
  const int l15 = lane & 15;
  f32x4 acc[4][2];
#pragma unroll
  for (int i = 0; i < 4; ++i)
#pragma unroll
    for (int j = 0; j < 2; ++j) acc[i][j] = (f32x4){0.f, 0.f, 0.f, 0.f};
#pragma unroll
  for (int k0 = 0; k0 < 256; k0 += 32) {
    f16x8 a[4], b[2];
#pragma unroll
    for (int mf = 0; mf < 4; ++mf)
      a[mf] = *reinterpret_cast<const f16x8*>(
          t2 + (((size_t)(rowb + (mf << 4) + l15)) << 8) + k0 + kgrp);
#pragma unroll
    for (int nf = 0; nf < 2; ++nf)
      b[nf] = *reinterpret_cast<const f16x8*>(
          wh + (size_t)(((nf << 4) + l15) << 8) + k0 + kgrp);
#pragma unroll
    for (int mf = 0; mf < 4; ++mf)
#pragma unroll
      for (int nf = 0; nf < 2; ++nf)
        acc[mf][nf] = __builtin_amdgcn_mfma_f32_16x16x32_f16(
            a[mf], b[nf], acc[mf][nf], 0, 0, 0);
  }
#pragma unroll
  for (int nf = 0; nf < 2; ++nf) {
    int c = (nf << 4) + l15;
    if (c < 24) {
      float bi = (c < 20) ? regb[c] : confb[c - 20];
#pragma unroll
      for (int mf = 0; mf < 4; ++mf)
#pragma unroll
        for (int r = 0; r < 4; ++r) {
          int m = rowb + (mf << 4) + ((lane >> 4) << 2) + r;
          hbuf[(size_t)m * 24 + c] = acc[mf][nf][r] + bi;
        }
    }
  }
}

// ------------------------------------------- cls head + sigmoid*sigmoid out
__global__ __launch_bounds__(256) void cls_scores(
    const unsigned short* __restrict__ t2,  // absolute rows (ws base)
    const unsigned short* __restrict__ wcw,
    const float* __restrict__ clsb,
    const float* __restrict__ hbuf,         // absolute rows
    float* __restrict__ outs, int gm_base) {
  const int t = threadIdx.x, lane = t & 63, wv = t >> 6;
  const int gm0 = gm_base + blockIdx.x * 256;
  int logW, mbase, lvl_off;
  if (gm0 < 131072) { logW = 7; mbase = 0; lvl_off = 0; }
  else if (gm0 < 163840) { logW = 6; mbase = 131072; lvl_off = 65536; }
  else if (gm0 < 172032) { logW = 5; mbase = 163840; lvl_off = 81920; }
  else if (gm0 < 174080) { logW = 4; mbase = 172032; lvl_off = 86016; }
  else { logW = 3; mbase = 174080; lvl_off = 87040; }
  const int logHW = 2 * logW, HWm1 = (1 << logHW) - 1;
  const int rowb = gm0 + wv * 64;
  const int kgrp = (lane >> 4) << 3;
  const int l15 = lane & 15;
  f32x4 acc[4][4];
#pragma unroll
  for (int i = 0; i < 4; ++i)
#pragma unroll
    for (int j = 0; j < 4; ++j) acc[i][j] = (f32x4){0.f, 0.f, 0.f, 0.f};
#pragma unroll
  for (int k0 = 0; k0 < 256; k0 += 32) {
    f16x8 a[4], b[4];
#pragma unroll
    for (int mf = 0; mf < 4; ++mf)
      a[mf] = *reinterpret_cast<const f16x8*>(
          t2 + (((size_t)(rowb + (mf << 4) + l15)) << 8) + k0 + kgrp);
#pragma unroll
    for (int nf = 0; nf < 4; ++nf)
      b[nf] = *reinterpret_cast<const f16x8*>(
          wcw + (size_t)(((nf << 4) + l15) << 8) + k0 + kgrp);
#pragma unroll
    for (int mf = 0; mf < 4; ++mf)
#pragma unroll
      for (int nf = 0; nf < 4; ++nf)
        acc[mf][nf] = __builtin_amdgcn_mfma_f32_16x16x32_f16(
            a[mf], b[nf], acc[mf][nf], 0, 0, 0);
  }
#pragma unroll
  for (int nf = 0; nf < 4; ++nf) {
    int c = (nf << 4) + l15;
    if (c < 60) {
      int ai = c / 15, ci = c - ai * 15;
      float bi = clsb[c];
#pragma unroll
      for (int mf = 0; mf < 4; ++mf)
#pragma unroll
        for (int r = 0; r < 4; ++r) {
          int m = rowb + (mf << 4) + ((lane >> 4) << 2) + r;
          float logit = acc[mf][nf][r] + bi;
          float conf = hbuf[(size_t)m * 24 + 20 + ai];
          float sc = sigmf(logit) * sigmf(conf);
          int lm = m - mbase;
          int b = lm >> logHW;
          int hw = lm & HWm1;
          int loc = lvl_off + (hw << 2) + ai;
          outs[(size_t)b * 1309440 + (size_t)loc * 15 + ci] = sc;
        }
    }
  }
}

// ------------------------------------------------- rbox decode, all levels
__global__ __launch_bounds__(256) void decode_all(
    const float* __restrict__ hbuf, float* __restrict__ outb) {
  int tid = blockIdx.x * 256 + threadIdx.x;
  if (tid >= 174592 * 4) return;
  int m = tid >> 2, a = tid & 3;
  int logW, mbase, lvl_off;
  float stride;
  if (m < 131072) { logW = 7; mbase = 0; lvl_off = 0; stride = 8.f; }
  else if (m < 163840) { logW = 6; mbase = 131072; lvl_off = 65536; stride = 16.f; }
  else if (m < 172032) { logW = 5; mbase = 163840; lvl_off = 81920; stride = 32.f; }
  else if (m < 174080) { logW = 4; mbase = 172032; lvl_off = 86016; stride = 64.f; }
  else { logW = 3; mbase = 174080; lvl_off = 87040; stride = 128.f; }
  const int logHW = 2 * logW;
  const float ANG[4] = {-0.39269908169872414f, 0.39269908169872414f,
                        1.1780972450961724f, 1.9634954084936207f};
  const float* d = hbuf + (size_t)m * 24 + a * 5;
  float dx = d[0], dy = d[1], dw = d[2], dh = d[3], da = d[4];
  int lm = m - mbase;
  int b = lm >> logHW, hw = lm & ((1 << logHW) - 1);
  int h = hw >> logW, w = hw & ((1 << logW) - 1);
  float ctr = 0.5f * (stride - 1.0f);
  float rx = w * stride + ctr, ry = h * stride + ctr;
  float rw = stride * 1.6329931618554521f;  // 4/sqrt(6)
  float rh = stride * 9.7979589711327124f;  // 4*sqrt(6)
  const float MR = 13.815510557964274f;     // |log(1e-6)|
  dw = fminf(fmaxf(dw, -MR), MR);
  dh = fminf(fmaxf(dh, -MR), MR);
  float gx = dx * rw + rx;
  float gy = dy * rh + ry;
  float gw = rw * expf(dw);
  float gh = rh * expf(dh);
  float v = da + ANG[a] + 0.7853981633974483f;
  float r = fmodf(v, 3.14159265358979323846f);
  if (r < 0.0f) r += 3.14159265358979323846f;
  float ga = r - 0.7853981633974483f;
  int loc = lvl_off + (hw << 2) + a;
  size_t base = (size_t)b * 436480 + (size_t)loc * 5;
  outb[base + 0] = gx;
  outb[base + 1] = gy;
  outb[base + 2] = gw;
  outb[base + 3] = gh;
  outb[base + 4] = ga;
}

// ============================================================================
extern "C" void kernel_launch(void* const* d_in, const int* in_sizes, int n_in,
                              void* d_out, int out_size, void* d_ws,
                              size_t ws_size, hipStream_t stream) {
  const float* feats[5];
  for (int i = 0; i < 5; ++i) feats[i] = (const float*)d_in[i];
  const float* reg_w0 = (const float*)d_in[5];
  const float* reg_b0 = (const float*)d_in[6];
  const float* reg_w1 = (const float*)d_in[7];
  const float* reg_b1 = (const float*)d_in[8];
  const float* cls_w0 = (const float*)d_in[9];
  const float* cls_b0 = (const float*)d_in[10];
  const float* cls_w1 = (const float*)d_in[11];
  const float* cls_b1 = (const float*)d_in[12];
  const float* reg_head_w = (const float*)d_in[13];
  const float* reg_head_b = (const float*)d_in[14];
  const float* cls_head_w = (const float*)d_in[15];
  const float* cls_head_b = (const float*)d_in[16];
  const float* conf_w = (const float*)d_in[17];
  const float* conf_b = (const float*)d_in[18];

  unsigned short* ws = (unsigned short*)d_ws;
  unsigned short* t1r = ws + 44695552ull;
  unsigned short* t1c = ws + 78249984ull;
  unsigned short* wt4 = ws + 111804416ull;
  unsigned short* wh = ws + 114163712ull;
  unsigned short* wc = ws + 114171904ull;
  unsigned short* zp = ws + 114188288ull;
  float* hbuf_all = (float*)((char*)d_ws + 228376704ull);

  prep_convw<<<9216, 256, 0, stream>>>(reg_w0, reg_w1, cls_w0, cls_w1, wt4);
  prep_small<<<97, 256, 0, stream>>>(cls_head_w, reg_head_w, conf_w, wc, wh,
                                     zp);
  to_nhwc_all<<<2728, 256, 0, stream>>>(feats[0], feats[1], feats[2], feats[3],
                                        feats[4], ws);

  float* scores = (float*)d_out;
  float* boxes = (float*)d_out + SCORES_TOTAL;

  static const int gbase[2] = {0, 131072};
  static const int gM[2] = {131072, 43520};
  for (int g = 0; g < 2; ++g) {
    const int base = gbase[g];
    const int M = gM[g];
    conv1f<<<dim3(M / 128, 2), 256, 0, stream>>>(
        ws, wt4 + 0ull * 589824, wt4 + 2ull * 589824, reg_b0, cls_b0, zp, t1r,
        t1c, base);
    conv2w<<<M / 128, 256, 0, stream>>>(t1r, wt4 + 1ull * 589824, reg_b1, zp,
                                        ws, base);
    head24_mfma<<<M / 256, 256, 0, stream>>>(
        ws + ((size_t)base << 8), wh, reg_head_b, conf_b,
        hbuf_all + (size_t)base * 24);
    conv2w<<<M / 128, 256, 0, stream>>>(t1c, wt4 + 3ull * 589824, cls_b1, zp,
                                        ws, base);
    cls_scores<<<M / 256, 256, 0, stream>>>(ws, wc, cls_head_b, hbuf_all,
                                            scores, base);
  }
  decode_all<<<(174592 * 4 + 255) / 256, 256, 0, stream>>>(hbuf_all, boxes);
}

// Round 10
// 1114.804 us; speedup vs baseline: 1.0604x; 1.0604x over previous
//
#include <hip/hip_runtime.h>

// ============================================================================
// RetinaNetHead (S2ANet-style rotated head), MI355X gfx950.
// R10: true depth-3 pipeline (T4): triple-buffered LDS (72KB), counted
//      s_waitcnt vmcnt(6) -- stage(ph+1) stays IN FLIGHT across the wait;
//      loads get ~2 full phases of slack (R8/R9 were both effective depth-1).
//      Plus icq-outer/kk-inner phase order: tap re-reads 1 phase apart ->
//      L2-hit (R9 kk-outer: 8 phases apart, working set > 4MB/XCD -> HBM).
// Everything else identical to R9 (BK=32, XOR swizzle rule#21, vectorized
// LDS epilogue, merged dispatches). fp32 accum; logits/decode fp32.
//
// vmcnt discipline: exactly 6 global_load_lds per wave per stage (conv1f:
// 2A+2BR+2BC; conv2w: 2A+4B). Last phase waits vmcnt(0).
//
// Level geometry: rows gm 0..174591; cum={0,131072,163840,172032,174080,174592}
// Workspace (ushort units), same footprint (~245.1MB):
//   [0) feats NHWC fp16 (reused as t2) | [44,695,552) t1r | [78,249,984) t1c
//   [111,804,416) conv w 4x[9][256][256] | [114,163,712) wh | [114,171,904) wc
//   [114,188,288) zp | byte 228,376,704: hbuf fp32 [174592][24]
// ============================================================================

typedef __attribute__((ext_vector_type(8))) _Float16 f16x8;
typedef __attribute__((ext_vector_type(4))) float f32x4;

#define SCORES_TOTAL 10475520ull  // 8*87296*15

__device__ __forceinline__ unsigned short f2h(float f) {
  union { _Float16 h; unsigned short u; } x;
  x.h = (_Float16)f;
  return x.u;
}

__device__ __forceinline__ float sigmf(float x) {
  return 1.0f / (1.0f + expf(-x));
}

__device__ __forceinline__ void gload_lds16(const unsigned short* g,
                                            unsigned short* l) {
  __builtin_amdgcn_global_load_lds(
      (const __attribute__((address_space(1))) unsigned int*)g,
      (__attribute__((address_space(3))) unsigned int*)l, 16, 0, 0);
}

__device__ __forceinline__ void lvl_lookup(int gm, int& logW, int& mbase) {
  if (gm < 131072) { logW = 7; mbase = 0; }
  else if (gm < 163840) { logW = 6; mbase = 131072; }
  else if (gm < 172032) { logW = 5; mbase = 163840; }
  else if (gm < 174080) { logW = 4; mbase = 172032; }
  else { logW = 3; mbase = 174080; }
}

// ---------------------------------------------------------------- weight prep
__global__ __launch_bounds__(256) void prep_convw(
    const float* __restrict__ w0, const float* __restrict__ w1,
    const float* __restrict__ w2, const float* __restrict__ w3,
    unsigned short* __restrict__ wtout) {
  int g = blockIdx.x * 256 + threadIdx.x;  // < 4*589824
  int q = g >> 16;
  int wsel = q / 9;
  int kk = q - wsel * 9;
  int r = g & 65535;
  int oc = r >> 8, ic = r & 255;
  const float* src = (wsel == 0) ? w0 : (wsel == 1) ? w1 : (wsel == 2) ? w2 : w3;
  float v = src[(size_t)(oc * 256 + ic) * 9 + kk];
  wtout[(size_t)wsel * 589824 + (size_t)((kk << 8) + oc) * 256 + ic] = f2h(v);
}

__global__ __launch_bounds__(256) void prep_small(
    const float* __restrict__ clsh, const float* __restrict__ regh,
    const float* __restrict__ confw,
    unsigned short* __restrict__ wc, unsigned short* __restrict__ wh,
    unsigned short* __restrict__ zp) {
  int g = blockIdx.x * 256 + threadIdx.x;
  if (g < 16384) {
    int row = g >> 8, ic = g & 255;
    float v = (row < 60) ? clsh[row * 256 + ic] : 0.0f;
    wc[g] = f2h(v);
  } else if (g < 24576) {
    int gg = g - 16384;
    int row = gg >> 8, ic = gg & 255;
    float v = 0.0f;
    if (row < 20) v = regh[row * 256 + ic];
    else if (row < 24) v = confw[(row - 20) * 256 + ic];
    wh[gg] = f2h(v);
  } else if (g < 24640) {
    zp[g - 24576] = 0;
  }
}

// ------------------------------- NCHW fp32 -> NHWC fp16, all levels merged
__global__ __launch_bounds__(256) void to_nhwc_all(
    const float* __restrict__ f0, const float* __restrict__ f1,
    const float* __restrict__ f2, const float* __restrict__ f3,
    const float* __restrict__ f4, unsigned short* __restrict__ out) {
  __shared__ unsigned short L[64][258];
  const int t = threadIdx.x;
  const int gm0 = blockIdx.x * 64;
  int logW, mbase;
  const float* in;
  if (gm0 < 131072) { logW = 7; mbase = 0; in = f0; }
  else if (gm0 < 163840) { logW = 6; mbase = 131072; in = f1; }
  else if (gm0 < 172032) { logW = 5; mbase = 163840; in = f2; }
  else if (gm0 < 174080) { logW = 4; mbase = 172032; in = f3; }
  else { logW = 3; mbase = 174080; in = f4; }
  const int logHW = 2 * logW;
  const int HW = 1 << logHW;
  const int lm0 = gm0 - mbase;
  const int b = lm0 >> logHW;
  const int hw0 = lm0 & (HW - 1);
#pragma unroll
  for (int it = 0; it < 16; ++it) {
    int c = it * 16 + (t >> 4);
    int j4 = (t & 15) * 4;
    float4 v = *reinterpret_cast<const float4*>(
        in + (size_t)(b * 256 + c) * HW + hw0 + j4);
    L[j4 + 0][c] = f2h(v.x);
    L[j4 + 1][c] = f2h(v.y);
    L[j4 + 2][c] = f2h(v.z);
    L[j4 + 3][c] = f2h(v.w);
  }
  __syncthreads();
#pragma unroll
  for (int it = 0; it < 16; ++it) {
    int j = it * 4 + (t >> 6);
    int c4 = (t & 63) * 4;
    unsigned v0 = (unsigned)L[j][c4 + 0] | ((unsigned)L[j][c4 + 1] << 16);
    unsigned v1 = (unsigned)L[j][c4 + 2] | ((unsigned)L[j][c4 + 3] << 16);
    uint2 v = make_uint2(v0, v1);
    *reinterpret_cast<uint2*>(out + ((size_t)(gm0 + j) << 8) + c4) = v;
  }
}

// ----------------- conv1 both towers fused: 128Mx128N, BK32, 3-deep pipeline
__global__ __launch_bounds__(256, 2) void conv1f(
    const unsigned short* __restrict__ xin,   // absolute rows [gm][256]
    const unsigned short* __restrict__ wtR,
    const unsigned short* __restrict__ wtC,
    const float* __restrict__ biasR, const float* __restrict__ biasC,
    const unsigned short* __restrict__ zp,
    unsigned short* __restrict__ outR,        // group-local rows
    unsigned short* __restrict__ outC, int gm_base) {
  __shared__ unsigned short pool[36864];  // A 3x4096 | BR 3x4096 | BC 3x4096
  const int t = threadIdx.x;
  const int lane = t & 63;
  const int wv = t >> 6;
  const int wm = wv >> 1, wn = wv & 1;
  const int gm0 = gm_base + blockIdx.x * 128;
  const int n0 = blockIdx.y << 7;
  int logW, mbase;
  lvl_lookup(gm0, logW, mbase);
  const int logHW = 2 * logW;
  const int H = 1 << logW, W = H;
  const int HWm1 = (1 << logHW) - 1, Wm1 = W - 1;

  const int srow = lane >> 2;                               // 0..15
  const int schk = (((lane & 3) ^ ((lane >> 3) & 3)) << 3); // swizzled src chunk
  int hjj[2], wjj[2];
  const unsigned short* aptrj[2];
  const unsigned short* bRj[2];
  const unsigned short* bCj[2];
  const int sldrow = (wv << 5);
#pragma unroll
  for (int j = 0; j < 2; ++j) {
    int gm = gm0 + sldrow + (j << 4) + srow;
    int lm = gm - mbase;
    int hw = lm & HWm1;
    hjj[j] = hw >> logW;
    wjj[j] = hw & Wm1;
    aptrj[j] = xin + ((size_t)gm << 8) + schk;
    int br = n0 + sldrow + (j << 4) + srow;
    bRj[j] = wtR + ((size_t)br << 8) + schk;
    bCj[j] = wtC + ((size_t)br << 8) + schk;
  }

  f32x4 accR[4][4], accC[4][4];
#pragma unroll
  for (int i = 0; i < 4; ++i)
#pragma unroll
    for (int j = 0; j < 4; ++j) {
      accR[i][j] = (f32x4){0.f, 0.f, 0.f, 0.f};
      accC[i][j] = (f32x4){0.f, 0.f, 0.f, 0.f};
    }

  const int arow = (wm << 6) + (lane & 15);
  const int brow = (wn << 6) + (lane & 15);
  const int sxor = ((lane & 15) >> 1) & 3;
  const int achk = (((lane >> 4) << 3)) ^ (sxor << 3);

  // phase p (0..71): icp = p/9 (ic0 = icp*32), kk = p%9 -> tap (dy,dx).
  // icq-OUTER/kk-INNER: same A rows re-read 1 phase apart -> L2-hot.
  auto STAGE = [&](int p, int buf) {
    int icp = p / 9;
    int kk = p - icp * 9;
    int k3 = kk / 3;
    int dy = k3 - 1, dxv = kk - k3 * 3 - 1;
    int moff = ((dy << logW) + dxv) << 8;
    int ic0 = icp << 5;
    int bko = (kk << 16) + ic0;
    const int ab = buf << 12;
#pragma unroll
    for (int j = 0; j < 2; ++j) {
      bool valid = ((unsigned)(hjj[j] + dy) < (unsigned)H) &
                   ((unsigned)(wjj[j] + dxv) < (unsigned)W);
      const unsigned short* g = valid ? (aptrj[j] + moff + ic0) : zp;
      gload_lds16(g, pool + ab + ((sldrow + (j << 4)) << 5));
    }
#pragma unroll
    for (int j = 0; j < 2; ++j) {
      gload_lds16(bRj[j] + bko, pool + 12288 + ab + ((sldrow + (j << 4)) << 5));
      gload_lds16(bCj[j] + bko, pool + 24576 + ab + ((sldrow + (j << 4)) << 5));
    }
  };

  STAGE(0, 0);
  STAGE(1, 1);

  int cbuf = 0;
#pragma unroll 1
  for (int ph = 0; ph < 72; ++ph) {
    // wait for stage(ph) only; stage(ph+1)'s 6 loads stay in flight
    if (ph < 71) asm volatile("s_waitcnt vmcnt(6)" ::: "memory");
    else         asm volatile("s_waitcnt vmcnt(0)" ::: "memory");
    __builtin_amdgcn_s_barrier();
    __builtin_amdgcn_sched_barrier(0);
    if (ph < 70) {
      int sb = cbuf + 2; if (sb >= 3) sb -= 3;
      STAGE(ph + 2, sb);
    }
    __builtin_amdgcn_sched_barrier(0);  // pin stage issue before compute
    const int cb = cbuf << 12;
    f16x8 a[4], bR[4], bC[4];
#pragma unroll
    for (int mf = 0; mf < 4; ++mf)
      a[mf] = *reinterpret_cast<const f16x8*>(
          pool + cb + ((arow + (mf << 4)) << 5) + achk);
#pragma unroll
    for (int nf = 0; nf < 4; ++nf) {
      bR[nf] = *reinterpret_cast<const f16x8*>(
          pool + 12288 + cb + ((brow + (nf << 4)) << 5) + achk);
      bC[nf] = *reinterpret_cast<const f16x8*>(
          pool + 24576 + cb + ((brow + (nf << 4)) << 5) + achk);
    }
#pragma unroll
    for (int mf = 0; mf < 4; ++mf)
#pragma unroll
      for (int nf = 0; nf < 4; ++nf) {
        accR[mf][nf] = __builtin_amdgcn_mfma_f32_16x16x32_f16(
            a[mf], bR[nf], accR[mf][nf], 0, 0, 0);
        accC[mf][nf] = __builtin_amdgcn_mfma_f32_16x16x32_f16(
            a[mf], bC[nf], accC[mf][nf], 0, 0, 0);
      }
    cbuf = (cbuf == 2) ? 0 : cbuf + 1;
  }
  __syncthreads();  // all reads retired before epilogue overwrites pool

  // ---- vectorized epilogue: acc -> LDS f16 -> 16B stores
  const int erow = t >> 1;
  const int ech = t & 1;
  const unsigned short* esrc =
      pool + ((((erow >> 6) << 1) + ech) << 12) + ((erow & 63) << 6);
  unsigned short* ep = pool + (wv << 12);
  const int eg = (lane >> 4) << 2;
  const int el = lane & 15;
  const int lrow0 = gm0 - gm_base;

#pragma unroll
  for (int nf = 0; nf < 4; ++nf) {
    float bi = biasR[n0 + (wn << 6) + (nf << 4) + el];
#pragma unroll
    for (int mf = 0; mf < 4; ++mf)
#pragma unroll
      for (int r = 0; r < 4; ++r)
        ep[((mf << 4) + eg + r) * 64 + (nf << 4) + el] =
            f2h(fmaxf(accR[mf][nf][r] + bi, 0.0f));
  }
  __syncthreads();
  {
    unsigned short* edst =
        outR + ((size_t)(lrow0 + erow) << 8) + n0 + (ech << 6);
#pragma unroll
    for (int q = 0; q < 8; ++q)
      reinterpret_cast<uint4*>(edst)[q] =
          reinterpret_cast<const uint4*>(esrc)[q];
  }
  __syncthreads();
#pragma unroll
  for (int nf = 0; nf < 4; ++nf) {
    float bi = biasC[n0 + (wn << 6) + (nf << 4) + el];
#pragma unroll
    for (int mf = 0; mf < 4; ++mf)
#pragma unroll
      for (int r = 0; r < 4; ++r)
        ep[((mf << 4) + eg + r) * 64 + (nf << 4) + el] =
            f2h(fmaxf(accC[mf][nf][r] + bi, 0.0f));
  }
  __syncthreads();
  {
    unsigned short* edst =
        outC + ((size_t)(lrow0 + erow) << 8) + n0 + (ech << 6);
#pragma unroll
    for (int q = 0; q < 8; ++q)
      reinterpret_cast<uint4*>(edst)[q] =
          reinterpret_cast<const uint4*>(esrc)[q];
  }
}

// ----------------- conv2: 128Mx256N block, BK32, 3-deep pipeline
__global__ __launch_bounds__(256, 2) void conv2w(
    const unsigned short* __restrict__ xin,  // group-local rows
    const unsigned short* __restrict__ wt,
    const float* __restrict__ bias,
    const unsigned short* __restrict__ zp,
    unsigned short* __restrict__ yout,       // absolute rows
    int gm_base) {
  __shared__ unsigned short pool[36864];     // A 3x4096 | B 3x8192
  const int t = threadIdx.x;
  const int lane = t & 63;
  const int wv = t >> 6;
  const int wm = wv >> 1, wn = wv & 1;       // wave tile 64M x 128N
  const int gm0 = gm_base + blockIdx.x * 128;
  int logW, mbase;
  lvl_lookup(gm0, logW, mbase);
  const int logHW = 2 * logW;
  const int H = 1 << logW, W = H;
  const int HWm1 = (1 << logHW) - 1, Wm1 = W - 1;

  const int srow = lane >> 2;
  const int schk = (((lane & 3) ^ ((lane >> 3) & 3)) << 3);
  int hjj[2], wjj[2];
  const unsigned short* aptrj[2];
  const int sldrow = (wv << 5);
#pragma unroll
  for (int j = 0; j < 2; ++j) {
    int gm = gm0 + sldrow + (j << 4) + srow;
    int lm = gm - mbase;
    int hw = lm & HWm1;
    hjj[j] = hw >> logW;
    wjj[j] = hw & Wm1;
    aptrj[j] = xin + ((size_t)(gm - gm_base) << 8) + schk;
  }
  const unsigned short* bpj[4];
#pragma unroll
  for (int j = 0; j < 4; ++j) {
    int row = (wv << 6) + (j << 4) + srow;   // 0..255
    bpj[j] = wt + ((size_t)row << 8) + schk;
  }

  f32x4 acc[4][8];
#pragma unroll
  for (int i = 0; i < 4; ++i)
#pragma unroll
    for (int j = 0; j < 8; ++j) acc[i][j] = (f32x4){0.f, 0.f, 0.f, 0.f};

  const int arow = (wm << 6) + (lane & 15);
  const int brow = (wn << 7) + (lane & 15);
  const int sxor = ((lane & 15) >> 1) & 3;
  const int achk = (((lane >> 4) << 3)) ^ (sxor << 3);

  auto STAGE = [&](int p, int buf) {
    int icp = p / 9;
    int kk = p - icp * 9;
    int k3 = kk / 3;
    int dy = k3 - 1, dxv = kk - k3 * 3 - 1;
    int moff = ((dy << logW) + dxv) << 8;
    int ic0 = icp << 5;
    int bko = (kk << 16) + ic0;
#pragma unroll
    for (int j = 0; j < 2; ++j) {
      bool valid = ((unsigned)(hjj[j] + dy) < (unsigned)H) &
                   ((unsigned)(wjj[j] + dxv) < (unsigned)W);
      const unsigned short* g = valid ? (aptrj[j] + moff + ic0) : zp;
      gload_lds16(g, pool + (buf << 12) + ((sldrow + (j << 4)) << 5));
    }
#pragma unroll
    for (int j = 0; j < 4; ++j)
      gload_lds16(bpj[j] + bko, pool + 12288 + (buf << 13) +
                                    (((wv << 6) + (j << 4)) << 5));
  };

  STAGE(0, 0);
  STAGE(1, 1);

  int cbuf = 0;
#pragma unroll 1
  for (int ph = 0; ph < 72; ++ph) {
    if (ph < 71) asm volatile("s_waitcnt vmcnt(6)" ::: "memory");
    else         asm volatile("s_waitcnt vmcnt(0)" ::: "memory");
    __builtin_amdgcn_s_barrier();
    __builtin_amdgcn_sched_barrier(0);
    if (ph < 70) {
      int sb = cbuf + 2; if (sb >= 3) sb -= 3;
      STAGE(ph + 2, sb);
    }
    __builtin_amdgcn_sched_barrier(0);
    const int cbA = cbuf << 12;
    const int cbB = cbuf << 13;
    f16x8 a[4], b[8];
#pragma unroll
    for (int mf = 0; mf < 4; ++mf)
      a[mf] = *reinterpret_cast<const f16x8*>(
          pool + cbA + ((arow + (mf << 4)) << 5) + achk);
#pragma unroll
    for (int nf = 0; nf < 8; ++nf)
      b[nf] = *reinterpret_cast<const f16x8*>(
          pool + 12288 + cbB + ((brow + (nf << 4)) << 5) + achk);
#pragma unroll
    for (int mf = 0; mf < 4; ++mf)
#pragma unroll
      for (int nf = 0; nf < 8; ++nf)
        acc[mf][nf] = __builtin_amdgcn_mfma_f32_16x16x32_f16(
            a[mf], b[nf], acc[mf][nf], 0, 0, 0);
    cbuf = (cbuf == 2) ? 0 : cbuf + 1;
  }
  __syncthreads();  // all reads retired before epilogue overwrites pool

  // ---- vectorized epilogue, two 64-col halves
  const int erow = t >> 1;
  const int ech = t & 1;
  const unsigned short* esrc =
      pool + ((((erow >> 6) << 1) + ech) << 12) + ((erow & 63) << 6);
  unsigned short* ep = pool + (wv << 12);
  const int eg = (lane >> 4) << 2;
  const int el = lane & 15;

#pragma unroll
  for (int h = 0; h < 2; ++h) {
    if (h) __syncthreads();
#pragma unroll
    for (int q4 = 0; q4 < 4; ++q4) {
      int nf = (h << 2) + q4;
      float bi = bias[(wn << 7) + (nf << 4) + el];
#pragma unroll
      for (int mf = 0; mf < 4; ++mf)
#pragma unroll
        for (int r = 0; r < 4; ++r)
          ep[((mf << 4) + eg + r) * 64 + (q4 << 4) + el] =
              f2h(fmaxf(acc[mf][nf][r] + bi, 0.0f));
    }
    __syncthreads();
    unsigned short* edst =
        yout + ((size_t)(gm0 + erow) << 8) + (ech << 7) + (h << 6);
#pragma unroll
    for (int q = 0; q < 8; ++q)
      reinterpret_cast<uint4*>(edst)[q] =
          reinterpret_cast<const uint4*>(esrc)[q];
  }
}

// -------------------------------------------- bbox(20)+conf(4) head -> hbuf
__global__ __launch_bounds__(256) void head24_mfma(
    const unsigned short* __restrict__ t2,  // group-local rows
    const unsigned short* __restrict__ wh,
    const float* __restrict__ regb, const float* __restrict__ confb,
    float* __restrict__ hbuf) {             // group-local rows
  const int t = threadIdx.x, lane = t & 63, wv = t >> 6;
  const int rowb = blockIdx.x * 256 + wv * 64;
  const int kgrp = (lane >> 4) << 3;
  const int l15 = lane & 15;
  f32x4 acc[4][2];
#pragma unroll
  for (int i = 0; i < 4; ++i)
#pragma unroll
    for (int j = 0; j < 2; ++j) acc[i][j] = (f32x4){0.f, 0.f, 0.f, 0.f};
#pragma unroll
  for (int k0 = 0; k0 < 256; k0 += 32) {
    f16x8 a[4], b[2];
#pragma unroll
    for (int mf = 0; mf < 4; ++mf)
      a[mf] = *reinterpret_cast<const f16x8*>(
          t2 + (((size_t)(rowb + (mf << 4) + l15)) << 8) + k0 + kgrp);
#pragma unroll
    for (int nf = 0; nf < 2; ++nf)
      b[nf] = *reinterpret_cast<const f16x8*>(
          wh + (size_t)(((nf << 4) + l15) << 8) + k0 + kgrp);
#pragma unroll
    for (int mf = 0; mf < 4; ++mf)
#pragma unroll
      for (int nf = 0; nf < 2; ++nf)
        acc[mf][nf] = __builtin_amdgcn_mfma_f32_16x16x32_f16(
            a[mf], b[nf], acc[mf][nf], 0, 0, 0);
  }
#pragma unroll
  for (int nf = 0; nf < 2; ++nf) {
    int c = (nf << 4) + l15;
    if (c < 24) {
      float bi = (c < 20) ? regb[c] : confb[c - 20];
#pragma unroll
      for (int mf = 0; mf < 4; ++mf)
#pragma unroll
        for (int r = 0; r < 4; ++r) {
          int m = rowb + (mf << 4) + ((lane >> 4) << 2) + r;
          hbuf[(size_t)m * 24 + c] = acc[mf][nf][r] + bi;
        }
    }
  }
}

// ------------------------------------------- cls head + sigmoid*sigmoid out
__global__ __launch_bounds__(256) void cls_scores(
    const unsigned short* __restrict__ t2,  // absolute rows (ws base)
    const unsigned short* __restrict__ wcw,
    const float* __restrict__ clsb,
    const float* __restrict__ hbuf,         // absolute rows
    float* __restrict__ outs, int gm_base) {
  const int t = threadIdx.x, lane = t & 63, wv = t >> 6;
  const int gm0 = gm_base + blockIdx.x * 256;
  int logW, mbase, lvl_off;
  if (gm0 < 131072) { logW = 7; mbase = 0; lvl_off = 0; }
  else if (gm0 < 163840) { logW = 6; mbase = 131072; lvl_off = 65536; }
  else if (gm0 < 172032) { logW = 5; mbase = 163840; lvl_off = 81920; }
  else if (gm0 < 174080) { logW = 4; mbase = 172032; lvl_off = 86016; }
  else { logW = 3; mbase = 174080; lvl_off = 87040; }
  const int logHW = 2 * logW, HWm1 = (1 << logHW) - 1;
  const int rowb = gm0 + wv * 64;
  const int kgrp = (lane >> 4) << 3;
  const int l15 = lane & 15;
  f32x4 acc[4][4];
#pragma unroll
  for (int i = 0; i < 4; ++i)
#pragma unroll
    for (int j = 0; j < 4; ++j) acc[i][j] = (f32x4){0.f, 0.f, 0.f, 0.f};
#pragma unroll
  for (int k0 = 0; k0 < 256; k0 += 32) {
    f16x8 a[4], b[4];
#pragma unroll
    for (int mf = 0; mf < 4; ++mf)
      a[mf] = *reinterpret_cast<const f16x8*>(
          t2 + (((size_t)(rowb + (mf << 4) + l15)) << 8) + k0 + kgrp);
#pragma unroll
    for (int nf = 0; nf < 4; ++nf)
      b[nf] = *reinterpret_cast<const f16x8*>(
          wcw + (size_t)(((nf << 4) + l15) << 8) + k0 + kgrp);
#pragma unroll
    for (int mf = 0; mf < 4; ++mf)
#pragma unroll
      for (int nf = 0; nf < 4; ++nf)
        acc[mf][nf] = __builtin_amdgcn_mfma_f32_16x16x32_f16(
            a[mf], b[nf], acc[mf][nf], 0, 0, 0);
  }
#pragma unroll
  for (int nf = 0; nf < 4; ++nf) {
    int c = (nf << 4) + l15;
    if (c < 60) {
      int ai = c / 15, ci = c - ai * 15;
      float bi = clsb[c];
#pragma unroll
      for (int mf = 0; mf < 4; ++mf)
#pragma unroll
        for (int r = 0; r < 4; ++r) {
          int m = rowb + (mf << 4) + ((lane >> 4) << 2) + r;
          float logit = acc[mf][nf][r] + bi;
          float conf = hbuf[(size_t)m * 24 + 20 + ai];
          float sc = sigmf(logit) * sigmf(conf);
          int lm = m - mbase;
          int b = lm >> logHW;
          int hw = lm & HWm1;
          int loc = lvl_off + (hw << 2) + ai;
          outs[(size_t)b * 1309440 + (size_t)loc * 15 + ci] = sc;
        }
    }
  }
}

// ------------------------------------------------- rbox decode, all levels
__global__ __launch_bounds__(256) void decode_all(
    const float* __restrict__ hbuf, float* __restrict__ outb) {
  int tid = blockIdx.x * 256 + threadIdx.x;
  if (tid >= 174592 * 4) return;
  int m = tid >> 2, a = tid & 3;
  int logW, mbase, lvl_off;
  float stride;
  if (m < 131072) { logW = 7; mbase = 0; lvl_off = 0; stride = 8.f; }
  else if (m < 163840) { logW = 6; mbase = 131072; lvl_off = 65536; stride = 16.f; }
  else if (m < 172032) { logW = 5; mbase = 163840; lvl_off = 81920; stride = 32.f; }
  else if (m < 174080) { logW = 4; mbase = 172032; lvl_off = 86016; stride = 64.f; }
  else { logW = 3; mbase = 174080; lvl_off = 87040; stride = 128.f; }
  const int logHW = 2 * logW;
  const float ANG[4] = {-0.39269908169872414f, 0.39269908169872414f,
                        1.1780972450961724f, 1.9634954084936207f};
  const float* d = hbuf + (size_t)m * 24 + a * 5;
  float dx = d[0], dy = d[1], dw = d[2], dh = d[3], da = d[4];
  int lm = m - mbase;
  int b = lm >> logHW, hw = lm & ((1 << logHW) - 1);
  int h = hw >> logW, w = hw & ((1 << logW) - 1);
  float ctr = 0.5f * (stride - 1.0f);
  float rx = w * stride + ctr, ry = h * stride + ctr;
  float rw = stride * 1.6329931618554521f;  // 4/sqrt(6)
  float rh = stride * 9.7979589711327124f;  // 4*sqrt(6)
  const float MR = 13.815510557964274f;     // |log(1e-6)|
  dw = fminf(fmaxf(dw, -MR), MR);
  dh = fminf(fmaxf(dh, -MR), MR);
  float gx = dx * rw + rx;
  float gy = dy * rh + ry;
  float gw = rw * expf(dw);
  float gh = rh * expf(dh);
  float v = da + ANG[a] + 0.7853981633974483f;
  float r = fmodf(v, 3.14159265358979323846f);
  if (r < 0.0f) r += 3.14159265358979323846f;
  float ga = r - 0.7853981633974483f;
  int loc = lvl_off + (hw << 2) + a;
  size_t base = (size_t)b * 436480 + (size_t)loc * 5;
  outb[base + 0] = gx;
  outb[base + 1] = gy;
  outb[base + 2] = gw;
  outb[base + 3] = gh;
  outb[base + 4] = ga;
}

// ============================================================================
extern "C" void kernel_launch(void* const* d_in, const int* in_sizes, int n_in,
                              void* d_out, int out_size, void* d_ws,
                              size_t ws_size, hipStream_t stream) {
  const float* feats[5];
  for (int i = 0; i < 5; ++i) feats[i] = (const float*)d_in[i];
  const float* reg_w0 = (const float*)d_in[5];
  const float* reg_b0 = (const float*)d_in[6];
  const float* reg_w1 = (const float*)d_in[7];
  const float* reg_b1 = (const float*)d_in[8];
  const float* cls_w0 = (const float*)d_in[9];
  const float* cls_b0 = (const float*)d_in[10];
  const float* cls_w1 = (const float*)d_in[11];
  const float* cls_b1 = (const float*)d_in[12];
  const float* reg_head_w = (const float*)d_in[13];
  const float* reg_head_b = (const float*)d_in[14];
  const float* cls_head_w = (const float*)d_in[15];
  const float* cls_head_b = (const float*)d_in[16];
  const float* conf_w = (const float*)d_in[17];
  const float* conf_b = (const float*)d_in[18];

  unsigned short* ws = (unsigned short*)d_ws;
  unsigned short* t1r = ws + 44695552ull;
  unsigned short* t1c = ws + 78249984ull;
  unsigned short* wt4 = ws + 111804416ull;
  unsigned short* wh = ws + 114163712ull;
  unsigned short* wc = ws + 114171904ull;
  unsigned short* zp = ws + 114188288ull;
  float* hbuf_all = (float*)((char*)d_ws + 228376704ull);

  prep_convw<<<9216, 256, 0, stream>>>(reg_w0, reg_w1, cls_w0, cls_w1, wt4);
  prep_small<<<97, 256, 0, stream>>>(cls_head_w, reg_head_w, conf_w, wc, wh,
                                     zp);
  to_nhwc_all<<<2728, 256, 0, stream>>>(feats[0], feats[1], feats[2], feats[3],
                                        feats[4], ws);

  float* scores = (float*)d_out;
  float* boxes = (float*)d_out + SCORES_TOTAL;

  static const int gbase[2] = {0, 131072};
  static const int gM[2] = {131072, 43520};
  for (int g = 0; g < 2; ++g) {
    const int base = gbase[g];
    const int M = gM[g];
    conv1f<<<dim3(M / 128, 2), 256, 0, stream>>>(
        ws, wt4 + 0ull * 589824, wt4 + 2ull * 589824, reg_b0, cls_b0, zp, t1r,
        t1c, base);
    conv2w<<<M / 128, 256, 0, stream>>>(t1r, wt4 + 1ull * 589824, reg_b1, zp,
                                        ws, base);
    head24_mfma<<<M / 256, 256, 0, stream>>>(
        ws + ((size_t)base << 8), wh, reg_head_b, conf_b,
        hbuf_all + (size_t)base * 24);
    conv2w<<<M / 128, 256, 0, stream>>>(t1c, wt4 + 3ull * 589824, cls_b1, zp,
                                        ws, base);
    cls_scores<<<M / 256, 256, 0, stream>>>(ws, wc, cls_head_b, hbuf_all,
                                            scores, base);
  }
  decode_all<<<(174592 * 4 + 255) / 256, 256, 0, stream>>>(hbuf_all, boxes);
}